// Round 1
// baseline (6821.307 us; speedup 1.0000x reference)
//
#include <hip/hip_runtime.h>

// ============================================================================
// GRU_29300266893722  (B=64, T=512, IN=256, H=1024, OUT=256)  -- MI355X gfx950
//
// Pipeline (all on `stream`, all state re-derived every launch; ws is 0xAA-
// poisoned before each call and flags are step-tagged so no init is needed):
//   K1 convert X fp32->bf16
//   K2 pack all 6 weight matrices into bf16 MFMA B-fragment layout
//   K3 batched input projections XH/XZ/XR = X@{Wx,Uz,Ur}^T + b   (bf16 MFMA)
//   K4 persistent scan kernel: 64 blocks = 4 batch-chains x 16 col-blocks.
//      2 device-wide producer/consumer phases per step, synchronized with
//      step-tagged flags + sc0sc1 (Infinity-Cache-coherent) loads/stores.
//      Wh fragments VGPR-resident; Vz/Vr streamed from (never-invalidated) L2.
//   K5 out = h @ Wo^T + bo in fp32 VALU (exact-ish, tiny)
//
// Theory: scan is latency-bound (1024 all-to-all hops through IF); predicted
// dur ~1.0-1.7 ms, MfmaUtil <5%, VALUBusy low.
// ============================================================================

#define BB 64
#define TT 512
#define KIN 256
#define HH 1024
#define NOUT 256

typedef float  f32x4 __attribute__((ext_vector_type(4)));
typedef short  s16x8 __attribute__((ext_vector_type(8)));
typedef unsigned int u32x4 __attribute__((ext_vector_type(4)));
typedef unsigned short u16x4 __attribute__((ext_vector_type(4)));

#define MFMA16(a, b, c) __builtin_amdgcn_mfma_f32_16x16x32_bf16((a), (b), (c), 0, 0, 0)

static __device__ __forceinline__ s16x8 as16(u32x4 v) { return __builtin_bit_cast(s16x8, v); }

static __device__ __forceinline__ unsigned short f2bf(float f) {
  unsigned u = __float_as_uint(f);
  u += 0x7FFFu + ((u >> 16) & 1u);   // round-to-nearest-even
  return (unsigned short)(u >> 16);
}
static __device__ __forceinline__ float bf2f(unsigned short h) {
  return __uint_as_float(((unsigned)h) << 16);
}

static __device__ __forceinline__ float tanh_fast(float x) {
  float xc = fminf(fmaxf(x, -15.f), 15.f);
  float e = __expf(2.f * xc);
  return (e - 1.f) / (e + 1.f);
}
static __device__ __forceinline__ float sigmoid_fast(float x) {
  float xc = fminf(fmaxf(x, -30.f), 30.f);
  return 1.f / (1.f + __expf(-xc));
}

// ---- Infinity-Cache-coherent (cross-XCD) access helpers --------------------
// sc0 sc1 => bypass L1+L2, serviced at the device coherence point (MALL/IF).
// Data stores are write-through; s_waitcnt vmcnt(0) then flag-store gives
// release ordering without any L2 flush (so L2-resident weights stay hot).

static __device__ __forceinline__ unsigned cc_load_u32(const unsigned* p) {
  unsigned v;
  asm volatile("global_load_dword %0, %1, off sc0 sc1\n\ts_waitcnt vmcnt(0)"
               : "=v"(v) : "v"(p) : "memory");
  return v;
}
static __device__ __forceinline__ void cc_load_b128(u32x4& d, const void* p) {
  asm volatile("global_load_dwordx4 %0, %1, off sc0 sc1" : "=v"(d) : "v"(p));
}
// ties 8 in-flight b128 loads to a single vmcnt(0): uses of a0..a7 are forced
// to come after the wait (data-dependence through the asm).
static __device__ __forceinline__ void cc_tie8(u32x4& a0, u32x4& a1, u32x4& a2, u32x4& a3,
                                               u32x4& a4, u32x4& a5, u32x4& a6, u32x4& a7) {
  asm volatile("s_waitcnt vmcnt(0)"
               : "+v"(a0), "+v"(a1), "+v"(a2), "+v"(a3),
                 "+v"(a4), "+v"(a5), "+v"(a6), "+v"(a7)
               :: "memory");
}
static __device__ __forceinline__ void cc_store_b64(void* p, unsigned long long v) {
  asm volatile("global_store_dwordx2 %0, %1, off sc0 sc1" :: "v"(p), "v"(v) : "memory");
}
static __device__ __forceinline__ void cc_store_u32(unsigned* p, unsigned v) {
  asm volatile("global_store_dword %0, %1, off sc0 sc1" :: "v"(p), "v"(v) : "memory");
}
static __device__ __forceinline__ void vm_drain() {
  asm volatile("s_waitcnt vmcnt(0)" ::: "memory");
}

// All 64 lanes poll the chain's 16 flags (lane reads flags[lane&15]); exits
// when every producer has published `target`. Guard-bounded: on protocol
// failure we produce garbage instead of hanging the harness.
static __device__ __forceinline__ void spin_flags(const unsigned* f, int cl, unsigned target) {
  int guard = 0;
  while (true) {
    unsigned v = cc_load_u32(f + cl);
    if (__all(v == target)) break;
    if (++guard > (1 << 22)) break;
  }
}

// ---- workspace layout ------------------------------------------------------
static constexpr size_t SZ_XP   = (size_t)TT * BB * HH * 2;       // 67,108,864
static constexpr size_t OFF_XH  = 0;
static constexpr size_t OFF_XZ  = OFF_XH + SZ_XP;
static constexpr size_t OFF_XR  = OFF_XZ + SZ_XP;
static constexpr size_t OFF_XB  = OFF_XR + SZ_XP;                 // X bf16
static constexpr size_t OFF_WHP = OFF_XB + (size_t)BB * TT * KIN * 2;
static constexpr size_t OFF_VZP = OFF_WHP + (size_t)HH * HH * 2;
static constexpr size_t OFF_VRP = OFF_VZP + (size_t)HH * HH * 2;
static constexpr size_t OFF_WXP = OFF_VRP + (size_t)HH * HH * 2;
static constexpr size_t OFF_UZP = OFF_WXP + (size_t)HH * KIN * 2;
static constexpr size_t OFF_URP = OFF_UZP + (size_t)HH * KIN * 2;
static constexpr size_t OFF_HB  = OFF_URP + (size_t)HH * KIN * 2; // 4*16*1024 bf16
static constexpr size_t OFF_HRB = OFF_HB + (size_t)4 * 16 * HH * 2;
static constexpr size_t OFF_FA  = OFF_HRB + (size_t)4 * 16 * HH * 2;
static constexpr size_t OFF_FB  = OFF_FA + 4096;
static constexpr size_t OFF_HF  = OFF_FB + 4096;                  // final h fp32

// ============================================================================
// K1: X fp32 -> bf16
// ============================================================================
__global__ void __launch_bounds__(256) k_convert_x(const float* __restrict__ X,
                                                   unsigned short* __restrict__ Xb) {
  size_t i = ((size_t)blockIdx.x * 256 + threadIdx.x) * 4;
  f32x4 v = *(const f32x4*)(X + i);
  u16x4 o = { f2bf(v[0]), f2bf(v[1]), f2bf(v[2]), f2bf(v[3]) };
  *(u16x4*)(Xb + i) = o;
}

// ============================================================================
// K2: pack weights W[1024][K] fp32 into bf16 MFMA B-fragment layout:
//   frag (ct, kk, lane) holds W[ct*16 + (lane&15)][kk*32 + (lane>>4)*8 + j]
//   stored at dst + ((ct*KK + kk)*64 + lane)*8 ushorts  (16 B each).
// z = 0..5 : Wh, Vz, Vr (K=1024) | Wx, Uz, Ur (K=256)
// ============================================================================
__global__ void __launch_bounds__(256) k_pack_w(
    const float* __restrict__ Wh, const float* __restrict__ Vz, const float* __restrict__ Vr,
    const float* __restrict__ Wx, const float* __restrict__ Uz, const float* __restrict__ Ur,
    unsigned short* __restrict__ Whp, unsigned short* __restrict__ Vzp, unsigned short* __restrict__ Vrp,
    unsigned short* __restrict__ Wxp, unsigned short* __restrict__ Uzp, unsigned short* __restrict__ Urp) {
  int z = blockIdx.y;
  const float* src; unsigned short* dst; int K;
  switch (z) {
    case 0: src = Wh; dst = Whp; K = 1024; break;
    case 1: src = Vz; dst = Vzp; K = 1024; break;
    case 2: src = Vr; dst = Vrp; K = 1024; break;
    case 3: src = Wx; dst = Wxp; K = 256;  break;
    case 4: src = Uz; dst = Uzp; K = 256;  break;
    default: src = Ur; dst = Urp; K = 256; break;
  }
  int KK = K >> 5;
  int total = 64 * KK * 64;
  int tau = blockIdx.x * 256 + threadIdx.x;
  if (tau >= total) return;
  int lane = tau & 63;
  int kk = (tau >> 6) % KK;
  int ct = tau / (KK * 64);
  int q = lane >> 4, cl = lane & 15;
  const float* s = src + (size_t)(ct * 16 + cl) * K + kk * 32 + q * 8;
  f32x4 v0 = *(const f32x4*)s;
  f32x4 v1 = *(const f32x4*)(s + 4);
  u32x4 o;
  o.x = (unsigned)f2bf(v0[0]) | ((unsigned)f2bf(v0[1]) << 16);
  o.y = (unsigned)f2bf(v0[2]) | ((unsigned)f2bf(v0[3]) << 16);
  o.z = (unsigned)f2bf(v1[0]) | ((unsigned)f2bf(v1[1]) << 16);
  o.w = (unsigned)f2bf(v1[2]) | ((unsigned)f2bf(v1[3]) << 16);
  *(u32x4*)(dst + (size_t)tau * 8) = o;
}

// ============================================================================
// K3: XH/XZ/XR[t][b][h] (bf16) = (X @ W^T + bias), W in {Wx,Uz,Ur}.
// Block tile 64 rows x 64 cols; A staged in LDS in fragment layout; B frags
// streamed from packed weights (L2-resident). grid = (512, 16, 3).
// ============================================================================
__global__ void __launch_bounds__(256) k_proj(
    const unsigned short* __restrict__ Xb,
    const unsigned short* __restrict__ Wxp, const unsigned short* __restrict__ Uzp,
    const unsigned short* __restrict__ Urp,
    const float* __restrict__ bx, const float* __restrict__ bz, const float* __restrict__ br,
    unsigned short* __restrict__ XH, unsigned short* __restrict__ XZ, unsigned short* __restrict__ XR) {
  __shared__ u32x4 As[4 * 8 * 64];  // 32 KB, [rt][kk][lane] 16B frags
  const int tid = threadIdx.x;
  const int mb = blockIdx.x, cb = blockIdx.y, mu = blockIdx.z;

#pragma unroll
  for (int i = 0; i < 8; ++i) {
    int fid = i * 256 + tid;
    int lane = fid & 63, kk = (fid >> 6) & 7, rt = fid >> 9;
    int q = lane >> 4, cl = lane & 15;
    int mrow = mb * 64 + rt * 16 + cl;
    As[fid] = *(const u32x4*)(Xb + (size_t)mrow * KIN + kk * 32 + q * 8);
  }
  __syncthreads();

  const int lane = tid & 63, w = tid >> 6;
  const int q = lane >> 4, cl = lane & 15;
  const unsigned short* Bp = (mu == 0) ? Wxp : (mu == 1) ? Uzp : Urp;
  const float* bias        = (mu == 0) ? bx  : (mu == 1) ? bz  : br;
  unsigned short* Dst      = (mu == 0) ? XH  : (mu == 1) ? XZ  : XR;

  f32x4 z4 = {0.f, 0.f, 0.f, 0.f};
  f32x4 acc[4] = {z4, z4, z4, z4};
  const int ctg = cb * 4 + w;
#pragma unroll
  for (int kk = 0; kk < 8; ++kk) {
    u32x4 b = *(const u32x4*)(Bp + ((size_t)(ctg * 8 + kk) * 64 + lane) * 8);
#pragma unroll
    for (int rt = 0; rt < 4; ++rt)
      acc[rt] = MFMA16(as16(As[(rt * 8 + kk) * 64 + lane]), as16(b), acc[rt]);
  }
  const int col = cb * 64 + w * 16 + cl;
  const float bv = bias[col];
#pragma unroll
  for (int rt = 0; rt < 4; ++rt) {
#pragma unroll
    for (int j = 0; j < 4; ++j) {
      int m = mb * 64 + rt * 16 + q * 4 + j;   // m = b*512 + t
      int t = m & (TT - 1), b = m >> 9;
      Dst[((size_t)t * BB + b) * HH + col] = f2bf(acc[rt][j] + bv);
    }
  }
}

// ============================================================================
// K4: persistent scan. 64 blocks x 256 threads.
//   block = (chain g = blk>>4, col-block c = blk&15): rows 16g..16g+15,
//   cols 64c..64c+63. Wave w: K-split kk in [8w,8w+8); owns col-tile w for
//   state (h,z fp32 in C/D layout registers).
// Per step t:
//   phase A: wait hr(t-1) flags -> h_tilde = tanh(xh + hr@Wh^T) -> h update
//            -> publish h (bf16, sc0sc1) -> flagA = t+1
//   phase B: wait h flags -> z,r = sig(x? + h@V?^T) -> publish hr -> flagB=t+1
// ============================================================================
__global__ void __launch_bounds__(256) k_scan(
    const unsigned short* __restrict__ XH, const unsigned short* __restrict__ XZ,
    const unsigned short* __restrict__ XR,
    const unsigned short* __restrict__ Whp, const unsigned short* __restrict__ Vzp,
    const unsigned short* __restrict__ Vrp,
    unsigned short* __restrict__ hball, unsigned short* __restrict__ hrball,
    unsigned* __restrict__ fAall, unsigned* __restrict__ fBall,
    float* __restrict__ hfinal) {
  __shared__ f32x4 redA[4][4][64];          // 16 KB
  __shared__ f32x4 redB[4][4][64];          // 16 KB
  __shared__ unsigned short packb[16 * 64]; // 2 KB

  const int tid = threadIdx.x;
  const int lane = tid & 63, w = tid >> 6;
  const int q = lane >> 4, cl = lane & 15;
  const int blk = blockIdx.x;
  const int g = blk >> 4, c = blk & 15;

  unsigned short* hb  = hball  + (size_t)g * 16 * HH;
  unsigned short* hrb = hrball + (size_t)g * 16 * HH;
  unsigned* fA = fAall + g * 64;
  unsigned* fB = fBall + g * 64;

  const int c4 = c * 4, kw = w * 8;

  // resident Wh fragments (128 VGPRs)
  u32x4 wh[4][8];
#pragma unroll
  for (int ct = 0; ct < 4; ++ct)
#pragma unroll
    for (int k = 0; k < 8; ++k)
      wh[ct][k] = *(const u32x4*)(Whp + (((size_t)(c4 + ct) * 32 + kw + k) * 64 + lane) * 8);

  const f32x4 z4 = {0.f, 0.f, 0.f, 0.f};
  f32x4 hreg = z4, zreg = z4;

  const int row0 = g * 16 + q * 4;        // +j = global batch row of owner tile
  const int hcol = c * 64 + w * 16 + cl;  // owner-tile column

  for (int t = 0; t < TT; ++t) {
    // ---------------- phase A ----------------
    unsigned short xh_u[4];
#pragma unroll
    for (int j = 0; j < 4; ++j)
      xh_u[j] = XH[((size_t)t * BB + row0 + j) * HH + hcol];

    f32x4 acc[4] = {z4, z4, z4, z4};
    if (t > 0) {
      spin_flags(fB, cl, (unsigned)t);
      u32x4 a0, a1, a2, a3, a4, a5, a6, a7;
      const unsigned short* ab = hrb + cl * HH + kw * 32 + q * 8;
      cc_load_b128(a0, ab + 0 * 32);
      cc_load_b128(a1, ab + 1 * 32);
      cc_load_b128(a2, ab + 2 * 32);
      cc_load_b128(a3, ab + 3 * 32);
      cc_load_b128(a4, ab + 4 * 32);
      cc_load_b128(a5, ab + 5 * 32);
      cc_load_b128(a6, ab + 6 * 32);
      cc_load_b128(a7, ab + 7 * 32);
      cc_tie8(a0, a1, a2, a3, a4, a5, a6, a7);
      u32x4 a[8] = {a0, a1, a2, a3, a4, a5, a6, a7};
#pragma unroll
      for (int k = 0; k < 8; ++k) {
        s16x8 av = as16(a[k]);
#pragma unroll
        for (int ct = 0; ct < 4; ++ct)
          acc[ct] = MFMA16(av, as16(wh[ct][k]), acc[ct]);
      }
    }
    // cross-wave K reduction
#pragma unroll
    for (int ct = 0; ct < 4; ++ct) redA[w][ct][lane] = acc[ct];
    __syncthreads();
    f32x4 S = redA[0][w][lane];
    S += redA[1][w][lane]; S += redA[2][w][lane]; S += redA[3][w][lane];

#pragma unroll
    for (int j = 0; j < 4; ++j) {
      float pre = S[j] + bf2f(xh_u[j]);
      float ht = tanh_fast(pre);
      float hn = zreg[j] * hreg[j] + (1.f - zreg[j]) * ht;
      hreg[j] = hn;
      packb[(q * 4 + j) * 64 + w * 16 + cl] = f2bf(hn);
    }
    __syncthreads();
    {
      int row = tid >> 4, colg = (tid & 15) * 4;
      unsigned long long v = *(const unsigned long long*)&packb[tid * 4];
      cc_store_b64(hb + row * HH + c * 64 + colg, v);
      vm_drain();
    }
    __syncthreads();
    if (tid == 0) cc_store_u32(fA + c, (unsigned)(t + 1));
    if (t == TT - 1) break;

    // ---------------- phase B ----------------
    unsigned short xz_u[4], xr_u[4];
#pragma unroll
    for (int j = 0; j < 4; ++j) {
      xz_u[j] = XZ[((size_t)t * BB + row0 + j) * HH + hcol];
      xr_u[j] = XR[((size_t)t * BB + row0 + j) * HH + hcol];
    }
    spin_flags(fA, cl, (unsigned)(t + 1));
    u32x4 b0, b1, b2, b3, b4, b5, b6, b7;
    const unsigned short* ab2 = hb + cl * HH + kw * 32 + q * 8;
    cc_load_b128(b0, ab2 + 0 * 32);
    cc_load_b128(b1, ab2 + 1 * 32);
    cc_load_b128(b2, ab2 + 2 * 32);
    cc_load_b128(b3, ab2 + 3 * 32);
    cc_load_b128(b4, ab2 + 4 * 32);
    cc_load_b128(b5, ab2 + 5 * 32);
    cc_load_b128(b6, ab2 + 6 * 32);
    cc_load_b128(b7, ab2 + 7 * 32);
    cc_tie8(b0, b1, b2, b3, b4, b5, b6, b7);
    u32x4 a2v[8] = {b0, b1, b2, b3, b4, b5, b6, b7};

    f32x4 az[4] = {z4, z4, z4, z4};
    f32x4 ar[4] = {z4, z4, z4, z4};
#pragma unroll
    for (int k = 0; k < 8; ++k) {
      s16x8 av = as16(a2v[k]);
#pragma unroll
      for (int ct = 0; ct < 4; ++ct) {
        u32x4 vz = *(const u32x4*)(Vzp + (((size_t)(c4 + ct) * 32 + kw + k) * 64 + lane) * 8);
        az[ct] = MFMA16(av, as16(vz), az[ct]);
        u32x4 vr = *(const u32x4*)(Vrp + (((size_t)(c4 + ct) * 32 + kw + k) * 64 + lane) * 8);
        ar[ct] = MFMA16(av, as16(vr), ar[ct]);
      }
    }
#pragma unroll
    for (int ct = 0; ct < 4; ++ct) {
      redA[w][ct][lane] = az[ct];
      redB[w][ct][lane] = ar[ct];
    }
    __syncthreads();
    f32x4 Sz = redA[0][w][lane];
    Sz += redA[1][w][lane]; Sz += redA[2][w][lane]; Sz += redA[3][w][lane];
    f32x4 Sr = redB[0][w][lane];
    Sr += redB[1][w][lane]; Sr += redB[2][w][lane]; Sr += redB[3][w][lane];

#pragma unroll
    for (int j = 0; j < 4; ++j) {
      float zv = sigmoid_fast(Sz[j] + bf2f(xz_u[j]));
      float rv = sigmoid_fast(Sr[j] + bf2f(xr_u[j]));
      float hrv = rv * hreg[j];
      zreg[j] = zv;
      packb[(q * 4 + j) * 64 + w * 16 + cl] = f2bf(hrv);
    }
    __syncthreads();
    {
      int row = tid >> 4, colg = (tid & 15) * 4;
      unsigned long long v = *(const unsigned long long*)&packb[tid * 4];
      cc_store_b64(hrb + row * HH + c * 64 + colg, v);
      vm_drain();
    }
    __syncthreads();
    if (tid == 0) cc_store_u32(fB + c, (unsigned)(t + 1));
  }

  // epilogue: final h in fp32 (plain stores; next kernel sees them via
  // kernel-boundary coherence)
#pragma unroll
  for (int j = 0; j < 4; ++j)
    hfinal[(size_t)(row0 + j) * HH + hcol] = hreg[j];
}

// ============================================================================
// K5: out[b][o] = dot(h[b,:], Wo[o,:]) + bo[o]   (fp32, exact)
// ============================================================================
__global__ void __launch_bounds__(256) k_out(const float* __restrict__ hf,
                                             const float* __restrict__ Wo,
                                             const float* __restrict__ bo,
                                             float* __restrict__ out) {
  __shared__ float hs[HH];
  const int b = blockIdx.x, tid = threadIdx.x;
  *(f32x4*)&hs[tid * 4] = *(const f32x4*)(hf + (size_t)b * HH + tid * 4);
  __syncthreads();
  float acc = bo[tid];
  const f32x4* wr = (const f32x4*)(Wo + (size_t)tid * HH);
#pragma unroll 8
  for (int k = 0; k < HH / 4; ++k) {
    f32x4 wv = wr[k];
    f32x4 hv = *(const f32x4*)&hs[k * 4];
    acc += wv[0] * hv[0] + wv[1] * hv[1] + wv[2] * hv[2] + wv[3] * hv[3];
  }
  out[(size_t)b * NOUT + tid] = acc;
}

// ============================================================================
extern "C" void kernel_launch(void* const* d_in, const int* in_sizes, int n_in,
                              void* d_out, int out_size, void* d_ws, size_t ws_size,
                              hipStream_t stream) {
  (void)in_sizes; (void)n_in; (void)out_size; (void)ws_size;
  const float* X  = (const float*)d_in[0];
  const float* Wx = (const float*)d_in[1];
  const float* bx = (const float*)d_in[2];
  const float* Wh = (const float*)d_in[3];
  const float* Uz = (const float*)d_in[4];
  const float* bz = (const float*)d_in[5];
  const float* Vz = (const float*)d_in[6];
  const float* Ur = (const float*)d_in[7];
  const float* br = (const float*)d_in[8];
  const float* Vr = (const float*)d_in[9];
  const float* Wo = (const float*)d_in[10];
  const float* bo = (const float*)d_in[11];

  char* ws = (char*)d_ws;
  unsigned short* XHp = (unsigned short*)(ws + OFF_XH);
  unsigned short* XZp = (unsigned short*)(ws + OFF_XZ);
  unsigned short* XRp = (unsigned short*)(ws + OFF_XR);
  unsigned short* Xb  = (unsigned short*)(ws + OFF_XB);
  unsigned short* Whp = (unsigned short*)(ws + OFF_WHP);
  unsigned short* Vzp = (unsigned short*)(ws + OFF_VZP);
  unsigned short* Vrp = (unsigned short*)(ws + OFF_VRP);
  unsigned short* Wxp = (unsigned short*)(ws + OFF_WXP);
  unsigned short* Uzp = (unsigned short*)(ws + OFF_UZP);
  unsigned short* Urp = (unsigned short*)(ws + OFF_URP);
  unsigned short* hbp  = (unsigned short*)(ws + OFF_HB);
  unsigned short* hrbp = (unsigned short*)(ws + OFF_HRB);
  unsigned* fAp = (unsigned*)(ws + OFF_FA);
  unsigned* fBp = (unsigned*)(ws + OFF_FB);
  float* hfp = (float*)(ws + OFF_HF);

  k_convert_x<<<8192, 256, 0, stream>>>(X, Xb);
  k_pack_w<<<dim3(512, 6), 256, 0, stream>>>(Wh, Vz, Vr, Wx, Uz, Ur,
                                             Whp, Vzp, Vrp, Wxp, Uzp, Urp);
  k_proj<<<dim3(512, 16, 3), 256, 0, stream>>>(Xb, Wxp, Uzp, Urp, bx, bz, br,
                                               XHp, XZp, XRp);
  k_scan<<<64, 256, 0, stream>>>(XHp, XZp, XRp, Whp, Vzp, Vrp,
                                 hbp, hrbp, fAp, fBp, hfp);
  k_out<<<64, 256, 0, stream>>>(hfp, Wo, bo, (float*)d_out);
}

// Round 3
// 5302.070 us; speedup vs baseline: 1.2865x; 1.2865x over previous
//
#include <hip/hip_runtime.h>

// ============================================================================
// GRU_29300266893722  (B=64, T=512, IN=256, H=1024, OUT=256)  -- MI355X gfx950
//
// R3: flagless tag-in-data exchange. 4 chains x 16 rows, 16 blocks/chain.
// Exchange buffers hold tagged dwords (bf16<<16 | step_tag). Producers fire
// sc0sc1 stores (no drain, no flags); consumers load + validate tags and
// retry. Removes 2 of ~4 IF round trips per hop and eliminates the hot
// flag-line serialization (polls spread over 4096 lines/chain).
// Wh + Vz VGPR-resident; Vr streamed from L2. sc0sc1 (device scope) only —
// R2 showed sc0-alone is NOT coherent across CUs (SE scope, stale L1).
// ============================================================================

#define BB 64
#define TT 512
#define KIN 256
#define HH 1024
#define NOUT 256

typedef float  f32x4 __attribute__((ext_vector_type(4)));
typedef short  s16x8 __attribute__((ext_vector_type(8)));
typedef unsigned int u32x4 __attribute__((ext_vector_type(4)));
typedef unsigned short u16x4 __attribute__((ext_vector_type(4)));

#define MFMA16(a, b, c) __builtin_amdgcn_mfma_f32_16x16x32_bf16((a), (b), (c), 0, 0, 0)

static __device__ __forceinline__ s16x8 as16(u32x4 v) { return __builtin_bit_cast(s16x8, v); }

static __device__ __forceinline__ unsigned short f2bf(float f) {
  unsigned u = __float_as_uint(f);
  u += 0x7FFFu + ((u >> 16) & 1u);   // round-to-nearest-even
  return (unsigned short)(u >> 16);
}
static __device__ __forceinline__ float bf2f(unsigned short h) {
  return __uint_as_float(((unsigned)h) << 16);
}

static __device__ __forceinline__ float tanh_fast(float x) {
  float xc = fminf(fmaxf(x, -15.f), 15.f);
  float e = __expf(2.f * xc);
  return (e - 1.f) / (e + 1.f);
}
static __device__ __forceinline__ float sigmoid_fast(float x) {
  float xc = fminf(fmaxf(x, -30.f), 30.f);
  return 1.f / (1.f + __expf(-xc));
}

// ---- device-scope (IF-coherent) access helpers -----------------------------
static __device__ __forceinline__ void st_dw(unsigned* p, unsigned v) {
  asm volatile("global_store_dword %0, %1, off sc0 sc1" :: "v"(p), "v"(v) : "memory");
}
template <int OFF>
static __device__ __forceinline__ void ld128o(u32x4& d, const unsigned* p) {
  asm volatile("global_load_dwordx4 %0, %1, off offset:%2 sc0 sc1"
               : "=v"(d) : "v"(p), "i"(OFF));
}
static __device__ __forceinline__ void tie16(u32x4& a0, u32x4& a1, u32x4& a2, u32x4& a3,
                                             u32x4& a4, u32x4& a5, u32x4& a6, u32x4& a7,
                                             u32x4& a8, u32x4& a9, u32x4& aA, u32x4& aB,
                                             u32x4& aC, u32x4& aD, u32x4& aE, u32x4& aF) {
  asm volatile("s_waitcnt vmcnt(0)"
               : "+v"(a0), "+v"(a1), "+v"(a2), "+v"(a3),
                 "+v"(a4), "+v"(a5), "+v"(a6), "+v"(a7),
                 "+v"(a8), "+v"(a9), "+v"(aA), "+v"(aB),
                 "+v"(aC), "+v"(aD), "+v"(aE), "+v"(aF)
               :: "memory");
}

// pack two tagged-dword quads into one bf16x8 fragment register quad:
// result comp = (hi16(dB) << 16) | hi16(dA)
static __device__ __forceinline__ unsigned pk(unsigned hi, unsigned lo) {
  return __builtin_amdgcn_perm(hi, lo, 0x07060302u);
}
static __device__ __forceinline__ u32x4 pack_frag(u32x4 a, u32x4 b) {
  u32x4 r;
  r.x = pk(a.y, a.x); r.y = pk(a.w, a.z);
  r.z = pk(b.y, b.x); r.w = pk(b.w, b.z);
  return r;
}

// Load one wave's A-operand slice (8 frags = 64 tagged dwords per lane) and
// retry until every dword carries `tag`. Bounded: on timeout sets dead and
// proceeds (garbage, no hang; replay passes without ws re-poison fast-fail).
static __device__ __forceinline__ void load_validated(
    const unsigned* rp, unsigned tag, bool& dead, u32x4 (&a)[8]) {
  u32x4 r0, r1, r2, r3, r4, r5, r6, r7, r8, r9, rA, rB, rC, rD, rE, rF;
  int guard = 0;
  while (true) {
    ld128o<0 * 4>(r0, rp);   ld128o<4 * 4>(r1, rp);
    ld128o<32 * 4>(r2, rp);  ld128o<36 * 4>(r3, rp);
    ld128o<64 * 4>(r4, rp);  ld128o<68 * 4>(r5, rp);
    ld128o<96 * 4>(r6, rp);  ld128o<100 * 4>(r7, rp);
    ld128o<128 * 4>(r8, rp); ld128o<132 * 4>(r9, rp);
    ld128o<160 * 4>(rA, rp); ld128o<164 * 4>(rB, rp);
    ld128o<192 * 4>(rC, rp); ld128o<196 * 4>(rD, rp);
    ld128o<224 * 4>(rE, rp); ld128o<228 * 4>(rF, rp);
    tie16(r0, r1, r2, r3, r4, r5, r6, r7, r8, r9, rA, rB, rC, rD, rE, rF);
    unsigned bad = 0;
#define CHK(R) bad |= (R.x ^ tag) | (R.y ^ tag) | (R.z ^ tag) | (R.w ^ tag)
    CHK(r0); CHK(r1); CHK(r2); CHK(r3); CHK(r4); CHK(r5); CHK(r6); CHK(r7);
    CHK(r8); CHK(r9); CHK(rA); CHK(rB); CHK(rC); CHK(rD); CHK(rE); CHK(rF);
#undef CHK
    bad &= 0xFFFFu;
    if (__all(bad == 0)) break;
    if (dead || ++guard > 4096) { dead = true; break; }
  }
  a[0] = pack_frag(r0, r1); a[1] = pack_frag(r2, r3);
  a[2] = pack_frag(r4, r5); a[3] = pack_frag(r6, r7);
  a[4] = pack_frag(r8, r9); a[5] = pack_frag(rA, rB);
  a[6] = pack_frag(rC, rD); a[7] = pack_frag(rE, rF);
}

// ---- workspace layout ------------------------------------------------------
static constexpr size_t SZ_XP   = (size_t)TT * BB * HH * 2;       // 64 MB
static constexpr size_t OFF_XH  = 0;
static constexpr size_t OFF_XZ  = OFF_XH + SZ_XP;
static constexpr size_t OFF_XR  = OFF_XZ + SZ_XP;
static constexpr size_t OFF_XB  = OFF_XR + SZ_XP;                 // X bf16
static constexpr size_t OFF_WHP = OFF_XB + (size_t)BB * TT * KIN * 2;
static constexpr size_t OFF_VZP = OFF_WHP + (size_t)HH * HH * 2;
static constexpr size_t OFF_VRP = OFF_VZP + (size_t)HH * HH * 2;
static constexpr size_t OFF_WXP = OFF_VRP + (size_t)HH * HH * 2;
static constexpr size_t OFF_UZP = OFF_WXP + (size_t)HH * KIN * 2;
static constexpr size_t OFF_URP = OFF_UZP + (size_t)HH * KIN * 2;
static constexpr size_t OFF_HB  = OFF_URP + (size_t)HH * KIN * 2; // 4*16*1024 tagged dwords
static constexpr size_t OFF_HRB = OFF_HB + (size_t)4 * 16 * HH * 4;
static constexpr size_t OFF_HF  = OFF_HRB + (size_t)4 * 16 * HH * 4;  // final h fp32

// ============================================================================
// K1: X fp32 -> bf16
// ============================================================================
__global__ void __launch_bounds__(256) k_convert_x(const float* __restrict__ X,
                                                   unsigned short* __restrict__ Xb) {
  size_t i = ((size_t)blockIdx.x * 256 + threadIdx.x) * 4;
  f32x4 v = *(const f32x4*)(X + i);
  u16x4 o = { f2bf(v[0]), f2bf(v[1]), f2bf(v[2]), f2bf(v[3]) };
  *(u16x4*)(Xb + i) = o;
}

// ============================================================================
// K2: pack weights W[1024][K] fp32 -> bf16 MFMA B-fragment layout:
//   frag (ct, kk, lane) = W[ct*16 + (lane&15)][kk*32 + (lane>>4)*8 + j]
//   at dst + ((ct*KK + kk)*64 + lane)*8 ushorts.
// ============================================================================
__global__ void __launch_bounds__(256) k_pack_w(
    const float* __restrict__ Wh, const float* __restrict__ Vz, const float* __restrict__ Vr,
    const float* __restrict__ Wx, const float* __restrict__ Uz, const float* __restrict__ Ur,
    unsigned short* __restrict__ Whp, unsigned short* __restrict__ Vzp, unsigned short* __restrict__ Vrp,
    unsigned short* __restrict__ Wxp, unsigned short* __restrict__ Uzp, unsigned short* __restrict__ Urp) {
  int z = blockIdx.y;
  const float* src; unsigned short* dst; int K;
  switch (z) {
    case 0: src = Wh; dst = Whp; K = 1024; break;
    case 1: src = Vz; dst = Vzp; K = 1024; break;
    case 2: src = Vr; dst = Vrp; K = 1024; break;
    case 3: src = Wx; dst = Wxp; K = 256;  break;
    case 4: src = Uz; dst = Uzp; K = 256;  break;
    default: src = Ur; dst = Urp; K = 256; break;
  }
  int KK = K >> 5;
  int total = 64 * KK * 64;
  int tau = blockIdx.x * 256 + threadIdx.x;
  if (tau >= total) return;
  int lane = tau & 63;
  int kk = (tau >> 6) % KK;
  int ct = tau / (KK * 64);
  int q = lane >> 4, cl = lane & 15;
  const float* s = src + (size_t)(ct * 16 + cl) * K + kk * 32 + q * 8;
  f32x4 v0 = *(const f32x4*)s;
  f32x4 v1 = *(const f32x4*)(s + 4);
  u32x4 o;
  o.x = (unsigned)f2bf(v0[0]) | ((unsigned)f2bf(v0[1]) << 16);
  o.y = (unsigned)f2bf(v0[2]) | ((unsigned)f2bf(v0[3]) << 16);
  o.z = (unsigned)f2bf(v1[0]) | ((unsigned)f2bf(v1[1]) << 16);
  o.w = (unsigned)f2bf(v1[2]) | ((unsigned)f2bf(v1[3]) << 16);
  *(u32x4*)(dst + (size_t)tau * 8) = o;
}

// ============================================================================
// K3: XH/XZ/XR[t][b][h] (bf16) = X @ {Wx,Uz,Ur}^T + bias.  grid (512,16,3).
// ============================================================================
__global__ void __launch_bounds__(256) k_proj(
    const unsigned short* __restrict__ Xb,
    const unsigned short* __restrict__ Wxp, const unsigned short* __restrict__ Uzp,
    const unsigned short* __restrict__ Urp,
    const float* __restrict__ bx, const float* __restrict__ bz, const float* __restrict__ br,
    unsigned short* __restrict__ XH, unsigned short* __restrict__ XZ, unsigned short* __restrict__ XR) {
  __shared__ u32x4 As[4 * 8 * 64];  // 32 KB
  const int tid = threadIdx.x;
  const int mb = blockIdx.x, cb = blockIdx.y, mu = blockIdx.z;

#pragma unroll
  for (int i = 0; i < 8; ++i) {
    int fid = i * 256 + tid;
    int lane = fid & 63, kk = (fid >> 6) & 7, rt = fid >> 9;
    int q = lane >> 4, cl = lane & 15;
    int mrow = mb * 64 + rt * 16 + cl;
    As[fid] = *(const u32x4*)(Xb + (size_t)mrow * KIN + kk * 32 + q * 8);
  }
  __syncthreads();

  const int lane = tid & 63, w = tid >> 6;
  const int q = lane >> 4, cl = lane & 15;
  const unsigned short* Bp = (mu == 0) ? Wxp : (mu == 1) ? Uzp : Urp;
  const float* bias        = (mu == 0) ? bx  : (mu == 1) ? bz  : br;
  unsigned short* Dst      = (mu == 0) ? XH  : (mu == 1) ? XZ  : XR;

  f32x4 z4 = {0.f, 0.f, 0.f, 0.f};
  f32x4 acc[4] = {z4, z4, z4, z4};
  const int ctg = cb * 4 + w;
#pragma unroll
  for (int kk = 0; kk < 8; ++kk) {
    u32x4 b = *(const u32x4*)(Bp + ((size_t)(ctg * 8 + kk) * 64 + lane) * 8);
#pragma unroll
    for (int rt = 0; rt < 4; ++rt)
      acc[rt] = MFMA16(as16(As[(rt * 8 + kk) * 64 + lane]), as16(b), acc[rt]);
  }
  const int col = cb * 64 + w * 16 + cl;
  const float bv = bias[col];
#pragma unroll
  for (int rt = 0; rt < 4; ++rt) {
#pragma unroll
    for (int j = 0; j < 4; ++j) {
      int m = mb * 64 + rt * 16 + q * 4 + j;   // m = b*512 + t
      int t = m & (TT - 1), b = m >> 9;
      Dst[((size_t)t * BB + b) * HH + col] = f2bf(acc[rt][j] + bv);
    }
  }
}

// ============================================================================
// K4: persistent scan, tag-in-data protocol.  64 blocks x 256 threads.
//   chain g = blk>>4 (batch rows 16g..16g+15), col-block c = blk&15
//   (cols 64c..64c+63).  wave w: K-slice [256w, 256w+256), owns state for
//   output cols c*64 + w*16 + (lane&15), rows (lane>>4)*4+j  (C/D layout).
// Per step t:
//   phase A: load hrb (tag t, skip at t=0) -> h~ = tanh(xh + hr@Wh^T)
//            -> h = z*h + (1-z)*h~ -> store hb tagged t+1 (fire+forget)
//   phase B: load hb (tag t+1) -> z,r = sig(x? + h@V?^T)
//            -> store hrb = r*h tagged t+1
// ============================================================================
__global__ void __launch_bounds__(256, 1) k_scan(
    const unsigned short* __restrict__ XH, const unsigned short* __restrict__ XZ,
    const unsigned short* __restrict__ XR,
    const unsigned short* __restrict__ Whp, const unsigned short* __restrict__ Vzp,
    const unsigned short* __restrict__ Vrp,
    unsigned* __restrict__ hb32all, unsigned* __restrict__ hrb32all,
    float* __restrict__ hfinal) {
  __shared__ f32x4 redA[16 * 64];  // 16 KB
  __shared__ f32x4 redB[16 * 64];  // 16 KB
  __shared__ f32x4 redC[16 * 64];  // 16 KB

  const int tid = threadIdx.x;
  const int lane = tid & 63, w = tid >> 6;
  const int q = lane >> 4, cl = lane & 15;
  const int blk = blockIdx.x;
  const int g = blk >> 4, c = blk & 15;   // chain, col-block
  const int c4 = c * 4, kw = w * 8;

  unsigned* hb  = hb32all  + (size_t)g * 16 * HH;
  unsigned* hrb = hrb32all + (size_t)g * 16 * HH;

  // resident weight fragments: Wh + Vz (256 VGPRs); Vr streamed per step
  u32x4 wh[4][8], vz[4][8];
#pragma unroll
  for (int ct = 0; ct < 4; ++ct)
#pragma unroll
    for (int k = 0; k < 8; ++k) {
      size_t fi = (((size_t)(c4 + ct) * 32 + kw + k) * 64 + lane) * 8;
      wh[ct][k] = *(const u32x4*)(Whp + fi);
      vz[ct][k] = *(const u32x4*)(Vzp + fi);
    }

  const int hcol = c * 64 + w * 16 + cl;         // owned output column
  const int brow0 = g * 16 + q * 4;              // owned batch rows (+j)
  const unsigned* rpA = hrb + (size_t)cl * HH + kw * 32 + q * 8;  // A-frag read base
  const unsigned* rpB = hb  + (size_t)cl * HH + kw * 32 + q * 8;
  unsigned* spA = hb  + (size_t)(q * 4) * HH + hcol;   // store base (rows q*4+j)
  unsigned* spB = hrb + (size_t)(q * 4) * HH + hcol;

  const f32x4 z4 = {0.f, 0.f, 0.f, 0.f};
  f32x4 hreg = z4, zreg = z4;
  bool dead = false;

  for (int t = 0; t < TT; ++t) {
    // ---------------- phase A: h update ----------------
    unsigned short xh_u[4];
#pragma unroll
    for (int j = 0; j < 4; ++j)
      xh_u[j] = XH[((size_t)t * BB + brow0 + j) * HH + hcol];

    f32x4 acc[4] = {z4, z4, z4, z4};
    if (t > 0) {
      u32x4 a[8];
      load_validated(rpA, (unsigned)t, dead, a);
#pragma unroll
      for (int k = 0; k < 8; ++k) {
        s16x8 av = as16(a[k]);
#pragma unroll
        for (int ct = 0; ct < 4; ++ct)
          acc[ct] = MFMA16(av, as16(wh[ct][k]), acc[ct]);
      }
    }
#pragma unroll
    for (int ct = 0; ct < 4; ++ct) redA[(w * 4 + ct) * 64 + lane] = acc[ct];
    __syncthreads();
    f32x4 S = redA[(0 * 4 + w) * 64 + lane];
    S += redA[(1 * 4 + w) * 64 + lane];
    S += redA[(2 * 4 + w) * 64 + lane];
    S += redA[(3 * 4 + w) * 64 + lane];

    const unsigned tagn = (unsigned)(t + 1);
#pragma unroll
    for (int j = 0; j < 4; ++j) {
      float pre = S[j] + bf2f(xh_u[j]);
      float ht = tanh_fast(pre);
      float hn = zreg[j] * hreg[j] + (1.f - zreg[j]) * ht;
      hreg[j] = hn;
      st_dw(spA + (size_t)j * HH, ((unsigned)f2bf(hn) << 16) | tagn);
    }
    if (t == TT - 1) break;

    // ---------------- phase B: gates ----------------
    unsigned short xz_u[4], xr_u[4];
#pragma unroll
    for (int j = 0; j < 4; ++j) {
      xz_u[j] = XZ[((size_t)t * BB + brow0 + j) * HH + hcol];
      xr_u[j] = XR[((size_t)t * BB + brow0 + j) * HH + hcol];
    }
    u32x4 b[8];
    load_validated(rpB, tagn, dead, b);

    f32x4 az[4] = {z4, z4, z4, z4};
    f32x4 ar[4] = {z4, z4, z4, z4};
#pragma unroll
    for (int ct = 0; ct < 4; ++ct) {
      u32x4 vrk[8];
#pragma unroll
      for (int k = 0; k < 8; ++k)
        vrk[k] = *(const u32x4*)(Vrp + (((size_t)(c4 + ct) * 32 + kw + k) * 64 + lane) * 8);
#pragma unroll
      for (int k = 0; k < 8; ++k)
        az[ct] = MFMA16(as16(b[k]), as16(vz[ct][k]), az[ct]);
#pragma unroll
      for (int k = 0; k < 8; ++k)
        ar[ct] = MFMA16(as16(b[k]), as16(vrk[k]), ar[ct]);
    }
#pragma unroll
    for (int ct = 0; ct < 4; ++ct) {
      redB[(w * 4 + ct) * 64 + lane] = az[ct];
      redC[(w * 4 + ct) * 64 + lane] = ar[ct];
    }
    __syncthreads();
    f32x4 Sz = redB[(0 * 4 + w) * 64 + lane];
    Sz += redB[(1 * 4 + w) * 64 + lane];
    Sz += redB[(2 * 4 + w) * 64 + lane];
    Sz += redB[(3 * 4 + w) * 64 + lane];
    f32x4 Sr = redC[(0 * 4 + w) * 64 + lane];
    Sr += redC[(1 * 4 + w) * 64 + lane];
    Sr += redC[(2 * 4 + w) * 64 + lane];
    Sr += redC[(3 * 4 + w) * 64 + lane];

#pragma unroll
    for (int j = 0; j < 4; ++j) {
      float zv = sigmoid_fast(Sz[j] + bf2f(xz_u[j]));
      float rv = sigmoid_fast(Sr[j] + bf2f(xr_u[j]));
      zreg[j] = zv;
      st_dw(spB + (size_t)j * HH, ((unsigned)f2bf(rv * hreg[j]) << 16) | tagn);
    }
  }

  // epilogue: final h fp32 (plain stores; visible at kernel boundary)
#pragma unroll
  for (int j = 0; j < 4; ++j)
    hfinal[(size_t)(brow0 + j) * HH + hcol] = hreg[j];
}

// ============================================================================
// K5: out[b][o] = dot(h[b,:], Wo[o,:]) + bo[o]   (fp32)
// ============================================================================
__global__ void __launch_bounds__(256) k_out(const float* __restrict__ hf,
                                             const float* __restrict__ Wo,
                                             const float* __restrict__ bo,
                                             float* __restrict__ out) {
  __shared__ float hs[HH];
  const int b = blockIdx.x, tid = threadIdx.x;
  *(f32x4*)&hs[tid * 4] = *(const f32x4*)(hf + (size_t)b * HH + tid * 4);
  __syncthreads();
  float acc = bo[tid];
  const f32x4* wr = (const f32x4*)(Wo + (size_t)tid * HH);
#pragma unroll 8
  for (int k = 0; k < HH / 4; ++k) {
    f32x4 wv = wr[k];
    f32x4 hv = *(const f32x4*)&hs[k * 4];
    acc += wv[0] * hv[0] + wv[1] * hv[1] + wv[2] * hv[2] + wv[3] * hv[3];
  }
  out[(size_t)b * NOUT + tid] = acc;
}

// ============================================================================
extern "C" void kernel_launch(void* const* d_in, const int* in_sizes, int n_in,
                              void* d_out, int out_size, void* d_ws, size_t ws_size,
                              hipStream_t stream) {
  (void)in_sizes; (void)n_in; (void)out_size; (void)ws_size;
  const float* X  = (const float*)d_in[0];
  const float* Wx = (const float*)d_in[1];
  const float* bx = (const float*)d_in[2];
  const float* Wh = (const float*)d_in[3];
  const float* Uz = (const float*)d_in[4];
  const float* bz = (const float*)d_in[5];
  const float* Vz = (const float*)d_in[6];
  const float* Ur = (const float*)d_in[7];
  const float* br = (const float*)d_in[8];
  const float* Vr = (const float*)d_in[9];
  const float* Wo = (const float*)d_in[10];
  const float* bo = (const float*)d_in[11];

  char* ws = (char*)d_ws;
  unsigned short* XHp = (unsigned short*)(ws + OFF_XH);
  unsigned short* XZp = (unsigned short*)(ws + OFF_XZ);
  unsigned short* XRp = (unsigned short*)(ws + OFF_XR);
  unsigned short* Xb  = (unsigned short*)(ws + OFF_XB);
  unsigned short* Whp = (unsigned short*)(ws + OFF_WHP);
  unsigned short* Vzp = (unsigned short*)(ws + OFF_VZP);
  unsigned short* Vrp = (unsigned short*)(ws + OFF_VRP);
  unsigned short* Wxp = (unsigned short*)(ws + OFF_WXP);
  unsigned short* Uzp = (unsigned short*)(ws + OFF_UZP);
  unsigned short* Urp = (unsigned short*)(ws + OFF_URP);
  unsigned* hbp  = (unsigned*)(ws + OFF_HB);
  unsigned* hrbp = (unsigned*)(ws + OFF_HRB);
  float* hfp = (float*)(ws + OFF_HF);

  k_convert_x<<<8192, 256, 0, stream>>>(X, Xb);
  k_pack_w<<<dim3(512, 6), 256, 0, stream>>>(Wh, Vz, Vr, Wx, Uz, Ur,
                                             Whp, Vzp, Vrp, Wxp, Uzp, Urp);
  k_proj<<<dim3(512, 16, 3), 256, 0, stream>>>(Xb, Wxp, Uzp, Urp, bx, bz, br,
                                               XHp, XZp, XRp);
  k_scan<<<64, 256, 0, stream>>>(XHp, XZp, XRp, Whp, Vzp, Vrp,
                                 hbp, hrbp, hfp);
  k_out<<<64, 256, 0, stream>>>(hfp, Wo, bo, (float*)d_out);
}